// Round 1
// baseline (642.217 us; speedup 1.0000x reference)
//
#include <hip/hip_runtime.h>

#define BM 128
#define BN 128
#define BKC 32

static constexpr float LRC  = 0.3f;
static constexpr float AC   = (float)(0.3 * 1e-4);          // LR*DSBETA
static constexpr float OMAC = (float)(1.0 - 0.3 * 1e-4);    // 1 - LR*DSBETA
static constexpr float EPSC = 0.01f;                        // EPS_DS
static constexpr float ATC  = 0.9f;                         // AT

// ---------------- kernel 1: per-node rel_sum and ||w||^2 ----------------
__global__ __launch_bounds__(256) void k_node_stats(
    const float* __restrict__ W, const float* __restrict__ REL,
    float* __restrict__ rel_sum, float* __restrict__ wsq, int D)
{
    int k = blockIdx.x, t = threadIdx.x;
    const float* wrow = W + (size_t)k * D;
    const float* rrow = REL + (size_t)k * D;
    float r = 0.f, q = 0.f;
    for (int i = t; i < D; i += 256) { r += rrow[i]; float w = wrow[i]; q += w * w; }
    __shared__ float s1[256], s2[256];
    s1[t] = r; s2[t] = q; __syncthreads();
    for (int off = 128; off > 0; off >>= 1) {
        if (t < off) { s1[t] += s1[t + off]; s2[t] += s2[t + off]; }
        __syncthreads();
    }
    if (t == 0) { rel_sum[k] = s1[0]; wsq[k] = s2[0]; }
}

// ---------------- kernel 2: per-row ||x||^2 ----------------
__global__ __launch_bounds__(128) void k_row_stats(
    const float* __restrict__ X, float* __restrict__ xsq, int D)
{
    int b = blockIdx.x, t = threadIdx.x;
    const float* xrow = X + (size_t)b * D;
    float q = 0.f;
    for (int i = t; i < D; i += 128) { float x = xrow[i]; q += x * x; }
    __shared__ float s1[128];
    s1[t] = q; __syncthreads();
    for (int off = 64; off > 0; off >>= 1) {
        if (t < off) s1[t] += s1[t + off];
        __syncthreads();
    }
    if (t == 0) xsq[b] = s1[0];
}

// ---------------- kernel 3: tiled fp32 distance GEMM + fused act/max/argmax ---
__global__ __launch_bounds__(256) void k_gemm_act(
    const float* __restrict__ X, const float* __restrict__ W,
    const float* __restrict__ xsq, const float* __restrict__ wsq,
    const float* __restrict__ rs,
    float* __restrict__ pmax, int* __restrict__ pidx,
    int K, int D)
{
    __shared__ float As[BKC][BM + 4];
    __shared__ float Bs[BKC][BN + 4];
    __shared__ float redM[BM][16];
    __shared__ int   redI[BM][16];

    const int tid = threadIdx.x;
    const int ty = tid >> 4, tx = tid & 15;
    const int nk = K / BN;
    const int bx = blockIdx.x % nk;
    const int by = blockIdx.x / nk;
    const int b0 = by * BM, k0 = bx * BN;

    float acc[8][8];
#pragma unroll
    for (int i = 0; i < 8; i++)
#pragma unroll
        for (int j = 0; j < 8; j++) acc[i][j] = 0.f;

    const int lrow = tid >> 3;          // 0..31
    const int lcol = (tid & 7) << 2;    // 0,4,...,28

    for (int kd = 0; kd < D; kd += BKC) {
#pragma unroll
        for (int rr = 0; rr < 4; rr++) {
            int row = lrow + rr * 32;
            const float4 v = *(const float4*)(X + (size_t)(b0 + row) * D + kd + lcol);
            As[lcol + 0][row] = v.x; As[lcol + 1][row] = v.y;
            As[lcol + 2][row] = v.z; As[lcol + 3][row] = v.w;
        }
#pragma unroll
        for (int rr = 0; rr < 4; rr++) {
            int row = lrow + rr * 32;
            const float4 v = *(const float4*)(W + (size_t)(k0 + row) * D + kd + lcol);
            Bs[lcol + 0][row] = v.x; Bs[lcol + 1][row] = v.y;
            Bs[lcol + 2][row] = v.z; Bs[lcol + 3][row] = v.w;
        }
        __syncthreads();
#pragma unroll
        for (int kk = 0; kk < BKC; kk++) {
            const float4 a0 = *(const float4*)&As[kk][ty * 8];
            const float4 a1 = *(const float4*)&As[kk][ty * 8 + 4];
            const float4 c0 = *(const float4*)&Bs[kk][tx * 8];
            const float4 c1 = *(const float4*)&Bs[kk][tx * 8 + 4];
            float a[8], b[8];
            a[0] = a0.x; a[1] = a0.y; a[2] = a0.z; a[3] = a0.w;
            a[4] = a1.x; a[5] = a1.y; a[6] = a1.z; a[7] = a1.w;
            b[0] = c0.x; b[1] = c0.y; b[2] = c0.z; b[3] = c0.w;
            b[4] = c1.x; b[5] = c1.y; b[6] = c1.z; b[7] = c1.w;
#pragma unroll
            for (int i = 0; i < 8; i++)
#pragma unroll
                for (int j = 0; j < 8; j++)
                    acc[i][j] = fmaf(a[i], b[j], acc[i][j]);
        }
        __syncthreads();
    }

    // epilogue: act + per-row (within-tile) max/argmax, first-occurrence ties
    float rsv[8], wq[8];
#pragma unroll
    for (int j = 0; j < 8; j++) {
        int c = k0 + tx * 8 + j;
        rsv[j] = rs[c];
        wq[j]  = wsq[c];
    }
    const float invD = 1.f / (float)D;   // D power of two -> exact
#pragma unroll
    for (int i = 0; i < 8; i++) {
        int r = b0 + ty * 8 + i;
        float xq = xsq[r];
        float m = -1e30f; int mj = 0;
#pragma unroll
        for (int j = 0; j < 8; j++) {
            float dd = (xq + wq[j]) - 2.f * acc[i][j];
            float dw = dd * (rsv[j] * invD);
            if (dw != dw) dw = 0.f;                    // isnan -> 0
            float act = rsv[j] / ((rsv[j] + dw) + 1e-7f);
            if (act > m) { m = act; mj = j; }          // strict > keeps first
        }
        redM[ty * 8 + i][tx] = m;
        redI[ty * 8 + i][tx] = tx * 8 + mj;
    }
    __syncthreads();
    if (tid < BM) {
        float m = -1e30f; int mi = 0;
#pragma unroll
        for (int t2 = 0; t2 < 16; t2++) {              // ascending tx -> first occ.
            float v = redM[tid][t2];
            if (v > m) { m = v; mi = redI[tid][t2]; }
        }
        pmax[(size_t)(b0 + tid) * nk + bx] = m;
        pidx[(size_t)(b0 + tid) * nk + bx] = k0 + mi;
    }
}

// ---------------- kernel 4: final per-row reduce over k-tiles ----------------
__global__ __launch_bounds__(256) void k_rowmax(
    const float* __restrict__ pmax, const int* __restrict__ pidx, int nkt,
    int* __restrict__ idxb, int* __restrict__ highb, int B)
{
    int b = blockIdx.x * 256 + threadIdx.x;
    if (b >= B) return;
    float m = -1e30f; int mi = 0;
    for (int t = 0; t < nkt; t++) {                    // ascending tile -> first occ.
        float v = pmax[(size_t)b * nkt + t];
        if (v > m) { m = v; mi = pidx[(size_t)b * nkt + t]; }
    }
    idxb[b] = mi;
    highb[b] = (m >= ATC) ? 1 : 0;
}

// ---------------- kernel 5: segment sums (high and low) via atomics ----------
__global__ __launch_bounds__(128) void k_segsum(
    const float* __restrict__ X, const int* __restrict__ idxb,
    const int* __restrict__ highb,
    float* __restrict__ cnt, float* __restrict__ cnt_l,
    float* __restrict__ sums, float* __restrict__ sums_l, int D)
{
    int b = blockIdx.x;
    int node = idxb[b];
    int hi = highb[b];
    float* c = hi ? cnt : cnt_l;
    float* s = (hi ? sums : sums_l) + (size_t)node * D;
    if (threadIdx.x == 0) atomicAdd(c + node, 1.f);
    const float4* xv = (const float4*)(X + (size_t)b * D);
    for (int i = threadIdx.x; i < (D >> 2); i += 128) {
        float4 v = xv[i];
        atomicAdd(s + i * 4 + 0, v.x);
        atomicAdd(s + i * 4 + 1, v.y);
        atomicAdd(s + i * 4 + 2, v.z);
        atomicAdd(s + i * 4 + 3, v.w);
    }
}

// ---------------- kernel 6: per-node high-branch update (D == 512) -----------
__global__ __launch_bounds__(256) void k_high_update(
    const float* __restrict__ W, const float* __restrict__ MA,
    const float* __restrict__ REL, const float* __restrict__ NC,
    const float* __restrict__ cnt, const float* __restrict__ sums,
    float* __restrict__ outW, float* __restrict__ outMA,
    float* __restrict__ outREL, float* __restrict__ outNC,
    float* __restrict__ outLoss, int D, float invB)
{
    int k = blockIdx.x, t = threadIdx.x;
    size_t ro = (size_t)k * D;
    float c = cnt[k];
    __shared__ float sred[256];
    int t2 = t + 256;
    if (c > 0.f) {
        float mean0 = sums[ro + t]  / c;
        float mean1 = sums[ro + t2] / c;
        float w0 = W[ro + t],  w1 = W[ro + t2];
        float a0 = MA[ro + t], a1 = MA[ro + t2];
        float m0 = AC * fabsf(mean0 - w0) + OMAC * a0;
        float m1 = AC * fabsf(mean1 - w1) + OMAC * a1;

        // max
        sred[t] = fmaxf(m0, m1); __syncthreads();
        for (int off = 128; off > 0; off >>= 1) {
            if (t < off) sred[t] = fmaxf(sred[t], sred[t + off]);
            __syncthreads();
        }
        float mx = sred[0]; __syncthreads();
        // min
        sred[t] = fminf(m0, m1); __syncthreads();
        for (int off = 128; off > 0; off >>= 1) {
            if (t < off) sred[t] = fminf(sred[t], sred[t + off]);
            __syncthreads();
        }
        float mn = sred[0]; __syncthreads();
        // mean
        sred[t] = m0 + m1; __syncthreads();
        for (int off = 128; off > 0; off >>= 1) {
            if (t < off) sred[t] += sred[t + off];
            __syncthreads();
        }
        float av = sred[0] / (float)D; __syncthreads();

        float scale = EPSC * (mx - mn);
        float r0 = 1.f / (1.f + expf((m0 - av) / scale));
        float r1 = 1.f / (1.f + expf((m1 - av) / scale));
        float d0 = LRC * (mean0 - w0), d1 = LRC * (mean1 - w1);

        outW[ro + t]  = w0 + d0;  outW[ro + t2]  = w1 + d1;
        outMA[ro + t] = m0;       outMA[ro + t2] = m1;
        outREL[ro + t] = r0;      outREL[ro + t2] = r1;

        // loss partial
        sred[t] = d0 + d1; __syncthreads();
        for (int off = 128; off > 0; off >>= 1) {
            if (t < off) sred[t] += sred[t + off];
            __syncthreads();
        }
        if (t == 0) {
            atomicAdd(outLoss, sred[0] * invB);
            outNC[k] = 1.f;
        }
    } else {
        outW[ro + t]  = W[ro + t];   outW[ro + t2]  = W[ro + t2];
        outMA[ro + t] = MA[ro + t];  outMA[ro + t2] = MA[ro + t2];
        outREL[ro + t] = REL[ro + t]; outREL[ro + t2] = REL[ro + t2];
        if (t == 0) outNC[k] = NC[k];
    }
}

// ---------------- kernel 7: flags + prefix scan (single block) ---------------
__global__ __launch_bounds__(1024) void k_scan(
    const float* __restrict__ cnt_l, const float* __restrict__ outNC,
    int* __restrict__ low_ids, int* __restrict__ avail_ids,
    int* __restrict__ scal, int K)
{
    __shared__ int sL[1024], sA[1024];
    int t = threadIdx.x;
    int per = (K + 1023) / 1024;    // 4 here
    int base = t * per;
    int lv[8], av[8];
    int cl = 0, ca = 0;
    for (int j = 0; j < per; j++) {
        int k = base + j;
        int l = 0, a = 0;
        if (k < K) {
            l = (cnt_l[k] > 0.f) ? 1 : 0;
            a = (outNC[k] == 0.f) ? 1 : 0;
        }
        lv[j] = l; av[j] = a; cl += l; ca += a;
    }
    sL[t] = cl; sA[t] = ca; __syncthreads();
    for (int off = 1; off < 1024; off <<= 1) {
        int vL = (t >= off) ? sL[t - off] : 0;
        int vA = (t >= off) ? sA[t - off] : 0;
        __syncthreads();
        sL[t] += vL; sA[t] += vA;
        __syncthreads();
    }
    int totL = sL[1023], totA = sA[1023];
    int eL = sL[t] - cl, eA = sA[t] - ca;   // exclusive prefix for this chunk
    for (int j = 0; j < per; j++) {
        if (lv[j]) low_ids[eL++] = base + j;
        if (av[j]) avail_ids[eA++] = base + j;
    }
    if (t == 0) {
        scal[0] = totL;
        scal[1] = totA;
        scal[2] = (totL < totA) ? totL : totA;
    }
}

// ---------------- kernel 8: add-node scatter ---------------------------------
__global__ __launch_bounds__(128) void k_addnode(
    const float* __restrict__ cnt_l, const float* __restrict__ sums_l,
    const int* __restrict__ low_ids, const int* __restrict__ avail_ids,
    const int* __restrict__ scal,
    float* __restrict__ outW, float* __restrict__ outMA,
    float* __restrict__ outREL, float* __restrict__ outNC, int D)
{
    int r = blockIdx.x;
    int n_create = scal[2], n_new = scal[0];
    if (r >= n_create) return;
    int slot = avail_ids[r];
    int src  = low_ids[n_new - n_create + r];
    float c = cnt_l[src];
    size_t so = (size_t)src * D, to = (size_t)slot * D;
    for (int i = threadIdx.x; i < D; i += 128) {
        outW[to + i]  = sums_l[so + i] / c;
        outMA[to + i] = 0.f;
        outREL[to + i] = 1.f;
    }
    if (threadIdx.x == 0) outNC[slot] = 1.f;
}

// ---------------- launch -----------------------------------------------------
extern "C" void kernel_launch(void* const* d_in, const int* in_sizes, int n_in,
                              void* d_out, int out_size, void* d_ws, size_t ws_size,
                              hipStream_t stream) {
    const float* X   = (const float*)d_in[0];
    const float* W   = (const float*)d_in[1];
    const float* MA  = (const float*)d_in[2];
    const float* REL = (const float*)d_in[3];
    const float* NC  = (const float*)d_in[4];

    const int K = in_sizes[4];              // 4096
    const int D = in_sizes[1] / K;          // 512
    const int B = in_sizes[0] / D;          // 8192
    const int NKT = K / BN;                 // 32
    const size_t KD = (size_t)K * D;

    float* out = (float*)d_out;
    float* outLoss = out;
    float* outW   = out + 1;
    float* outMA  = out + 1 + KD;
    float* outREL = out + 1 + 2 * KD;
    float* outNC  = out + 1 + 3 * KD;

    float* wsf = (float*)d_ws;
    size_t off = 0;
    float* rel_sum = wsf + off; off += K;
    float* wsq     = wsf + off; off += K;
    float* xsq     = wsf + off; off += B;
    float* pmax    = wsf + off; off += (size_t)B * NKT;
    int*   pidx    = (int*)(wsf + off); off += (size_t)B * NKT;
    int*   idxb    = (int*)(wsf + off); off += B;
    int*   highb   = (int*)(wsf + off); off += B;
    int*   low_ids   = (int*)(wsf + off); off += K;
    int*   avail_ids = (int*)(wsf + off); off += K;
    int*   scal    = (int*)(wsf + off); off += 16;
    float* zero_base = wsf + off;
    float* cnt   = wsf + off; off += K;
    float* cnt_l = wsf + off; off += K;
    float* sums   = wsf + off; off += KD;
    float* sums_l = wsf + off; off += KD;

    hipMemsetAsync(zero_base, 0, (2 * (size_t)K + 2 * KD) * sizeof(float), stream);
    hipMemsetAsync(outLoss, 0, sizeof(float), stream);

    k_node_stats<<<K, 256, 0, stream>>>(W, REL, rel_sum, wsq, D);
    k_row_stats<<<B, 128, 0, stream>>>(X, xsq, D);
    k_gemm_act<<<(B / BM) * (K / BN), 256, 0, stream>>>(X, W, xsq, wsq, rel_sum,
                                                        pmax, pidx, K, D);
    k_rowmax<<<(B + 255) / 256, 256, 0, stream>>>(pmax, pidx, NKT, idxb, highb, B);
    k_segsum<<<B, 128, 0, stream>>>(X, idxb, highb, cnt, cnt_l, sums, sums_l, D);
    k_high_update<<<K, 256, 0, stream>>>(W, MA, REL, NC, cnt, sums,
                                         outW, outMA, outREL, outNC, outLoss,
                                         D, 1.f / (float)B);
    k_scan<<<1, 1024, 0, stream>>>(cnt_l, outNC, low_ids, avail_ids, scal, K);
    k_addnode<<<K, 128, 0, stream>>>(cnt_l, sums_l, low_ids, avail_ids, scal,
                                     outW, outMA, outREL, outNC, D);
}

// Round 3
// 441.409 us; speedup vs baseline: 1.4549x; 1.4549x over previous
//
#include <hip/hip_runtime.h>

typedef unsigned short ushort_t;
typedef unsigned int uint_t;
typedef __bf16 bf16x8 __attribute__((ext_vector_type(8)));
typedef float f32x4 __attribute__((ext_vector_type(4)));

#define BM 128
#define BN 128

static constexpr float LRC  = 0.3f;
static constexpr float AC   = (float)(0.3 * 1e-4);          // LR*DSBETA
static constexpr float OMAC = (float)(1.0 - 0.3 * 1e-4);    // 1 - LR*DSBETA
static constexpr float EPSC = 0.01f;                        // EPS_DS
static constexpr float ATC  = 0.9f;                         // AT

__device__ __forceinline__ void gll16(const void* g, void* l) {
    __builtin_amdgcn_global_load_lds((__attribute__((address_space(1))) void*)g,
                                     (__attribute__((address_space(3))) void*)l,
                                     16, 0, 0);
}

__device__ __forceinline__ ushort_t f2bf_rne(float f) {
    uint_t u = __float_as_uint(f);
    uint_t r = u + 0x7fffu + ((u >> 16) & 1u);
    return (ushort_t)(r >> 16);
}

// -------- kernel 0: fp32 -> (hi,mid,lo) bf16 3-way split ---------------------
__global__ __launch_bounds__(256) void k_split3(
    const float* __restrict__ src, ushort_t* __restrict__ hi,
    ushort_t* __restrict__ mid, ushort_t* __restrict__ lo, int n4)
{
    int i = blockIdx.x * 256 + threadIdx.x;
    int stride = gridDim.x * 256;
    for (; i < n4; i += stride) {
        float4 v = ((const float4*)src)[i];
        float x[4] = {v.x, v.y, v.z, v.w};
        ushort_t h[4], m[4], l[4];
#pragma unroll
        for (int j = 0; j < 4; j++) {
            h[j] = f2bf_rne(x[j]);
            float hf = __uint_as_float(((uint_t)h[j]) << 16);
            float r1 = x[j] - hf;                         // exact (Sterbenz)
            m[j] = f2bf_rne(r1);
            float mf = __uint_as_float(((uint_t)m[j]) << 16);
            float r2 = r1 - mf;                           // exact
            l[j] = f2bf_rne(r2);
        }
        ((ushort4*)hi)[i]  = make_ushort4(h[0], h[1], h[2], h[3]);
        ((ushort4*)mid)[i] = make_ushort4(m[0], m[1], m[2], m[3]);
        ((ushort4*)lo)[i]  = make_ushort4(l[0], l[1], l[2], l[3]);
    }
}

// ---------------- kernel 1: per-node rel_sum and ||w||^2 ----------------
__global__ __launch_bounds__(256) void k_node_stats(
    const float* __restrict__ W, const float* __restrict__ REL,
    float* __restrict__ rel_sum, float* __restrict__ wsq, int D)
{
    int k = blockIdx.x, t = threadIdx.x;
    const float* wrow = W + (size_t)k * D;
    const float* rrow = REL + (size_t)k * D;
    float r = 0.f, q = 0.f;
    for (int i = t; i < D; i += 256) { r += rrow[i]; float w = wrow[i]; q += w * w; }
    __shared__ float s1[256], s2[256];
    s1[t] = r; s2[t] = q; __syncthreads();
    for (int off = 128; off > 0; off >>= 1) {
        if (t < off) { s1[t] += s1[t + off]; s2[t] += s2[t + off]; }
        __syncthreads();
    }
    if (t == 0) { rel_sum[k] = s1[0]; wsq[k] = s2[0]; }
}

// ---------------- kernel 2: per-row ||x||^2 ----------------
__global__ __launch_bounds__(128) void k_row_stats(
    const float* __restrict__ X, float* __restrict__ xsq, int D)
{
    int b = blockIdx.x, t = threadIdx.x;
    const float* xrow = X + (size_t)b * D;
    float q = 0.f;
    for (int i = t; i < D; i += 128) { float x = xrow[i]; q += x * x; }
    __shared__ float s1[128];
    s1[t] = q; __syncthreads();
    for (int off = 64; off > 0; off >>= 1) {
        if (t < off) s1[t] += s1[t + off];
        __syncthreads();
    }
    if (t == 0) xsq[b] = s1[0];
}

// --- kernel 3: 3-way-split bf16 MFMA distance GEMM + fused act/max/argmax ----
// dot = hh + hm + mh + hl + lh + mm  (ml/lm/ll dropped, ~2^-27 rel)
__global__ __launch_bounds__(256, 2) void k_gemm_act(
    const ushort_t* __restrict__ Xh, const ushort_t* __restrict__ Xm,
    const ushort_t* __restrict__ Xl,
    const ushort_t* __restrict__ Wh, const ushort_t* __restrict__ Wm,
    const ushort_t* __restrict__ Wl,
    const float* __restrict__ xsq, const float* __restrict__ wsq,
    const float* __restrict__ rs,
    float* __restrict__ pmax, int* __restrict__ pidx,
    int K, int D)
{
    // 6 planes x (128 rows x 32 k x 2B) = 6 x 8192 B
    __shared__ char smem[49152];

    const int tid = threadIdx.x;
    const int wave = tid >> 6, lane = tid & 63;
    const int nk = K / BN;
    const int bx = blockIdx.x % nk, by = blockIdx.x / nk;
    const int b0 = by * BM, k0 = bx * BN;

    // staging: wave w stages rows [w*32, w*32+32) of each 128x32 tile
    const int srow = wave * 32 + (lane >> 2);
    const int scol = (lane & 3) * 8;
    const size_t gx = (size_t)(b0 + srow) * D + scol;
    const size_t gw = (size_t)(k0 + srow) * D + scol;
    const size_t c1 = (size_t)16 * D;     // second 16-row chunk
    char* lb = smem + wave * 2048;        // wave-uniform; HW adds lane*16

    // fragment LDS byte offsets (within a plane)
    const int wm = wave >> 1, wn = wave & 1;
    const int l15 = lane & 15, quad = lane >> 4;
    const int aoff = (wm * 64 + l15) * 64 + quad * 16;
    const int boff = (wn * 64 + l15) * 64 + quad * 16;

    f32x4 acc[4][4];
#pragma unroll
    for (int i = 0; i < 4; i++)
#pragma unroll
        for (int j = 0; j < 4; j++) acc[i][j] = (f32x4){0.f, 0.f, 0.f, 0.f};

    for (int kd = 0; kd < D; kd += 32) {
        gll16(Xh + gx + kd,      lb + 0);
        gll16(Xh + gx + c1 + kd, lb + 1024);
        gll16(Xm + gx + kd,      lb + 8192);
        gll16(Xm + gx + c1 + kd, lb + 8192 + 1024);
        gll16(Xl + gx + kd,      lb + 16384);
        gll16(Xl + gx + c1 + kd, lb + 16384 + 1024);
        gll16(Wh + gw + kd,      lb + 24576);
        gll16(Wh + gw + c1 + kd, lb + 24576 + 1024);
        gll16(Wm + gw + kd,      lb + 32768);
        gll16(Wm + gw + c1 + kd, lb + 32768 + 1024);
        gll16(Wl + gw + kd,      lb + 40960);
        gll16(Wl + gw + c1 + kd, lb + 40960 + 1024);
        __syncthreads();

        bf16x8 ah[4], am[4], al[4];
#pragma unroll
        for (int t = 0; t < 4; t++) {
            ah[t] = *(const bf16x8*)(smem + 0     + aoff + t * 1024);
            am[t] = *(const bf16x8*)(smem + 8192  + aoff + t * 1024);
            al[t] = *(const bf16x8*)(smem + 16384 + aoff + t * 1024);
        }
#pragma unroll
        for (int j = 0; j < 4; j++) {
            bf16x8 bh = *(const bf16x8*)(smem + 24576 + boff + j * 1024);
            bf16x8 bm = *(const bf16x8*)(smem + 32768 + boff + j * 1024);
            bf16x8 bl = *(const bf16x8*)(smem + 40960 + boff + j * 1024);
#pragma unroll
            for (int i = 0; i < 4; i++) {
                acc[i][j] = __builtin_amdgcn_mfma_f32_16x16x32_bf16(ah[i], bh, acc[i][j], 0, 0, 0);
                acc[i][j] = __builtin_amdgcn_mfma_f32_16x16x32_bf16(ah[i], bm, acc[i][j], 0, 0, 0);
                acc[i][j] = __builtin_amdgcn_mfma_f32_16x16x32_bf16(am[i], bh, acc[i][j], 0, 0, 0);
                acc[i][j] = __builtin_amdgcn_mfma_f32_16x16x32_bf16(ah[i], bl, acc[i][j], 0, 0, 0);
                acc[i][j] = __builtin_amdgcn_mfma_f32_16x16x32_bf16(al[i], bh, acc[i][j], 0, 0, 0);
                acc[i][j] = __builtin_amdgcn_mfma_f32_16x16x32_bf16(am[i], bm, acc[i][j], 0, 0, 0);
            }
        }
        __syncthreads();
    }

    // epilogue: act + per-row max/argmax (first-occurrence via k-tie rule)
    float rsv[4], wqv[4];
#pragma unroll
    for (int tn = 0; tn < 4; tn++) {
        int c = k0 + wn * 64 + tn * 16 + l15;
        rsv[tn] = rs[c]; wqv[tn] = wsq[c];
    }
    const float invD = 1.f / (float)D;
    float* redM = (float*)smem;          // [128][32], aliases tile LDS
    int*   redI = (int*)(smem + 16384);
#pragma unroll
    for (int tm = 0; tm < 4; tm++) {
#pragma unroll
        for (int r = 0; r < 4; r++) {
            int rowl = wm * 64 + tm * 16 + quad * 4 + r;
            float xq = xsq[b0 + rowl];
            float m = -1e30f; int mk = 0x7fffffff;
#pragma unroll
            for (int tn = 0; tn < 4; tn++) {
                float dot = acc[tm][tn][r];
                float dd = (xq + wqv[tn]) - 2.f * dot;
                float dw = dd * (rsv[tn] * invD);
                if (dw != dw) dw = 0.f;                       // isnan -> 0
                float act = rsv[tn] / ((rsv[tn] + dw) + 1e-7f);
                int kidx = k0 + wn * 64 + tn * 16 + l15;
                if (act > m || (act == m && kidx < mk)) { m = act; mk = kidx; }
            }
            redM[rowl * 32 + wn * 16 + l15] = m;
            redI[rowl * 32 + wn * 16 + l15] = mk;
        }
    }
    __syncthreads();
    if (tid < BM) {
        float m = -1e30f; int mk = 0x7fffffff;
#pragma unroll
        for (int t2 = 0; t2 < 32; t2++) {
            float v = redM[tid * 32 + t2]; int kv = redI[tid * 32 + t2];
            if (v > m || (v == m && kv < mk)) { m = v; mk = kv; }
        }
        pmax[(size_t)(b0 + tid) * nk + bx] = m;
        pidx[(size_t)(b0 + tid) * nk + bx] = mk;
    }
}

// ---------------- kernel 4: final per-row reduce over k-tiles ----------------
__global__ __launch_bounds__(256) void k_rowmax(
    const float* __restrict__ pmax, const int* __restrict__ pidx, int nkt,
    int* __restrict__ idxb, int* __restrict__ highb, int B)
{
    int b = blockIdx.x * 256 + threadIdx.x;
    if (b >= B) return;
    float m = -1e30f; int mi = 0x7fffffff;
    for (int t = 0; t < nkt; t++) {
        float v = pmax[(size_t)b * nkt + t];
        int kv = pidx[(size_t)b * nkt + t];
        if (v > m || (v == m && kv < mi)) { m = v; mi = kv; }
    }
    idxb[b] = mi;
    highb[b] = (m >= ATC) ? 1 : 0;
}

// ---------------- kernel 5: segment sums (high and low) via atomics ----------
__global__ __launch_bounds__(128) void k_segsum(
    const float* __restrict__ X, const int* __restrict__ idxb,
    const int* __restrict__ highb,
    float* __restrict__ cnt, float* __restrict__ cnt_l,
    float* __restrict__ sums, float* __restrict__ sums_l, int D)
{
    int b = blockIdx.x;
    int node = idxb[b];
    int hi = highb[b];
    float* c = hi ? cnt : cnt_l;
    float* s = (hi ? sums : sums_l) + (size_t)node * D;
    if (threadIdx.x == 0) atomicAdd(c + node, 1.f);
    const float4* xv = (const float4*)(X + (size_t)b * D);
    for (int i = threadIdx.x; i < (D >> 2); i += 128) {
        float4 v = xv[i];
        atomicAdd(s + i * 4 + 0, v.x);
        atomicAdd(s + i * 4 + 1, v.y);
        atomicAdd(s + i * 4 + 2, v.z);
        atomicAdd(s + i * 4 + 3, v.w);
    }
}

// ---------------- kernel 6: per-node high-branch update (D == 512) -----------
__global__ __launch_bounds__(256) void k_high_update(
    const float* __restrict__ W, const float* __restrict__ MA,
    const float* __restrict__ REL, const float* __restrict__ NC,
    const float* __restrict__ cnt, const float* __restrict__ sums,
    float* __restrict__ outW, float* __restrict__ outMA,
    float* __restrict__ outREL, float* __restrict__ outNC,
    float* __restrict__ outLoss, int D, float invB)
{
    int k = blockIdx.x, t = threadIdx.x;
    size_t ro = (size_t)k * D;
    float c = cnt[k];
    __shared__ float sred[256];
    int t2 = t + 256;
    if (c > 0.f) {
        float mean0 = sums[ro + t]  / c;
        float mean1 = sums[ro + t2] / c;
        float w0 = W[ro + t],  w1 = W[ro + t2];
        float a0 = MA[ro + t], a1 = MA[ro + t2];
        float m0 = AC * fabsf(mean0 - w0) + OMAC * a0;
        float m1 = AC * fabsf(mean1 - w1) + OMAC * a1;

        sred[t] = fmaxf(m0, m1); __syncthreads();
        for (int off = 128; off > 0; off >>= 1) {
            if (t < off) sred[t] = fmaxf(sred[t], sred[t + off]);
            __syncthreads();
        }
        float mx = sred[0]; __syncthreads();
        sred[t] = fminf(m0, m1); __syncthreads();
        for (int off = 128; off > 0; off >>= 1) {
            if (t < off) sred[t] = fminf(sred[t], sred[t + off]);
            __syncthreads();
        }
        float mn = sred[0]; __syncthreads();
        sred[t] = m0 + m1; __syncthreads();
        for (int off = 128; off > 0; off >>= 1) {
            if (t < off) sred[t] += sred[t + off];
            __syncthreads();
        }
        float av = sred[0] / (float)D; __syncthreads();

        float scale = EPSC * (mx - mn);
        float r0 = 1.f / (1.f + expf((m0 - av) / scale));
        float r1 = 1.f / (1.f + expf((m1 - av) / scale));
        float d0 = LRC * (mean0 - w0), d1 = LRC * (mean1 - w1);

        outW[ro + t]  = w0 + d0;  outW[ro + t2]  = w1 + d1;
        outMA[ro + t] = m0;       outMA[ro + t2] = m1;
        outREL[ro + t] = r0;      outREL[ro + t2] = r1;

        sred[t] = d0 + d1; __syncthreads();
        for (int off = 128; off > 0; off >>= 1) {
            if (t < off) sred[t] += sred[t + off];
            __syncthreads();
        }
        if (t == 0) {
            atomicAdd(outLoss, sred[0] * invB);
            outNC[k] = 1.f;
        }
    } else {
        outW[ro + t]  = W[ro + t];   outW[ro + t2]  = W[ro + t2];
        outMA[ro + t] = MA[ro + t];  outMA[ro + t2] = MA[ro + t2];
        outREL[ro + t] = REL[ro + t]; outREL[ro + t2] = REL[ro + t2];
        if (t == 0) outNC[k] = NC[k];
    }
}

// ---------------- kernel 7: flags + prefix scan (single block) ---------------
__global__ __launch_bounds__(1024) void k_scan(
    const float* __restrict__ cnt_l, const float* __restrict__ outNC,
    int* __restrict__ low_ids, int* __restrict__ avail_ids,
    int* __restrict__ scal, int K)
{
    __shared__ int sL[1024], sA[1024];
    int t = threadIdx.x;
    int per = (K + 1023) / 1024;
    int base = t * per;
    int lv[8], av[8];
    int cl = 0, ca = 0;
    for (int j = 0; j < per; j++) {
        int k = base + j;
        int l = 0, a = 0;
        if (k < K) {
            l = (cnt_l[k] > 0.f) ? 1 : 0;
            a = (outNC[k] == 0.f) ? 1 : 0;
        }
        lv[j] = l; av[j] = a; cl += l; ca += a;
    }
    sL[t] = cl; sA[t] = ca; __syncthreads();
    for (int off = 1; off < 1024; off <<= 1) {
        int vL = (t >= off) ? sL[t - off] : 0;
        int vA = (t >= off) ? sA[t - off] : 0;
        __syncthreads();
        sL[t] += vL; sA[t] += vA;
        __syncthreads();
    }
    int totL = sL[1023], totA = sA[1023];
    int eL = sL[t] - cl, eA = sA[t] - ca;
    for (int j = 0; j < per; j++) {
        if (lv[j]) low_ids[eL++] = base + j;
        if (av[j]) avail_ids[eA++] = base + j;
    }
    if (t == 0) {
        scal[0] = totL;
        scal[1] = totA;
        scal[2] = (totL < totA) ? totL : totA;
    }
}

// ---------------- kernel 8: add-node scatter ---------------------------------
__global__ __launch_bounds__(128) void k_addnode(
    const float* __restrict__ cnt_l, const float* __restrict__ sums_l,
    const int* __restrict__ low_ids, const int* __restrict__ avail_ids,
    const int* __restrict__ scal,
    float* __restrict__ outW, float* __restrict__ outMA,
    float* __restrict__ outREL, float* __restrict__ outNC, int D)
{
    int r = blockIdx.x;
    int n_create = scal[2], n_new = scal[0];
    if (r >= n_create) return;
    int slot = avail_ids[r];
    int src  = low_ids[n_new - n_create + r];
    float c = cnt_l[src];
    size_t so = (size_t)src * D, to = (size_t)slot * D;
    for (int i = threadIdx.x; i < D; i += 128) {
        outW[to + i]  = sums_l[so + i] / c;
        outMA[to + i] = 0.f;
        outREL[to + i] = 1.f;
    }
    if (threadIdx.x == 0) outNC[slot] = 1.f;
}

// ---------------- launch -----------------------------------------------------
extern "C" void kernel_launch(void* const* d_in, const int* in_sizes, int n_in,
                              void* d_out, int out_size, void* d_ws, size_t ws_size,
                              hipStream_t stream) {
    const float* X   = (const float*)d_in[0];
    const float* W   = (const float*)d_in[1];
    const float* MA  = (const float*)d_in[2];
    const float* REL = (const float*)d_in[3];
    const float* NC  = (const float*)d_in[4];

    const int K = in_sizes[4];              // 4096
    const int D = in_sizes[1] / K;          // 512
    const int B = in_sizes[0] / D;          // 8192
    const int NKT = K / BN;                 // 32
    const size_t KD = (size_t)K * D;
    const size_t BD = (size_t)B * D;

    float* out = (float*)d_out;
    float* outLoss = out;
    float* outW   = out + 1;
    float* outMA  = out + 1 + KD;
    float* outREL = out + 1 + 2 * KD;
    float* outNC  = out + 1 + 3 * KD;

    float* wsf = (float*)d_ws;
    size_t off = 0;
    ushort_t* Xh = (ushort_t*)(wsf + off); off += BD / 2;
    ushort_t* Xm = (ushort_t*)(wsf + off); off += BD / 2;
    ushort_t* Xl = (ushort_t*)(wsf + off); off += BD / 2;
    ushort_t* Wh = (ushort_t*)(wsf + off); off += KD / 2;
    ushort_t* Wm = (ushort_t*)(wsf + off); off += KD / 2;
    ushort_t* Wl = (ushort_t*)(wsf + off); off += KD / 2;
    float* rel_sum = wsf + off; off += K;
    float* wsq     = wsf + off; off += K;
    float* xsq     = wsf + off; off += B;
    float* pmax    = wsf + off; off += (size_t)B * NKT;
    int*   pidx    = (int*)(wsf + off); off += (size_t)B * NKT;
    int*   idxb    = (int*)(wsf + off); off += B;
    int*   highb   = (int*)(wsf + off); off += B;
    int*   low_ids   = (int*)(wsf + off); off += K;
    int*   avail_ids = (int*)(wsf + off); off += K;
    int*   scal    = (int*)(wsf + off); off += 16;
    float* zero_base = wsf + off;
    float* cnt   = wsf + off; off += K;
    float* cnt_l = wsf + off; off += K;
    float* sums   = wsf + off; off += KD;
    float* sums_l = wsf + off; off += KD;

    hipMemsetAsync(zero_base, 0, (2 * (size_t)K + 2 * KD) * sizeof(float), stream);
    hipMemsetAsync(outLoss, 0, sizeof(float), stream);

    k_split3<<<2048, 256, 0, stream>>>(X, Xh, Xm, Xl, (int)(BD / 4));
    k_split3<<<1024, 256, 0, stream>>>(W, Wh, Wm, Wl, (int)(KD / 4));
    k_node_stats<<<K, 256, 0, stream>>>(W, REL, rel_sum, wsq, D);
    k_row_stats<<<B, 128, 0, stream>>>(X, xsq, D);
    k_gemm_act<<<(B / BM) * (K / BN), 256, 0, stream>>>(Xh, Xm, Xl, Wh, Wm, Wl,
                                                        xsq, wsq, rel_sum,
                                                        pmax, pidx, K, D);
    k_rowmax<<<(B + 255) / 256, 256, 0, stream>>>(pmax, pidx, NKT, idxb, highb, B);
    k_segsum<<<B, 128, 0, stream>>>(X, idxb, highb, cnt, cnt_l, sums, sums_l, D);
    k_high_update<<<K, 256, 0, stream>>>(W, MA, REL, NC, cnt, sums,
                                         outW, outMA, outREL, outNC, outLoss,
                                         D, 1.f / (float)B);
    k_scan<<<1, 1024, 0, stream>>>(cnt_l, outNC, low_ids, avail_ids, scal, K);
    k_addnode<<<K, 128, 0, stream>>>(cnt_l, sums_l, low_ids, avail_ids, scal,
                                     outW, outMA, outREL, outNC, D);
}